// Round 1
// 119.948 us; speedup vs baseline: 1.2805x; 1.2805x over previous
//
#include <hip/hip_runtime.h>

#define HH 128
#define WW 128
#define NPIX 16384
#define NC 32
#define NO 32
#define KS 9
#define TAPS 81
#define DIL 2
#define PAD 8
#define SMAX 27.6310211159f   // s <= SMAX <=> exp(-0.5 s) >= 1e-6; dropped-tap bound ~1.4e-5 << 8.8e-4
#define NW (NO * NC * TAPS)   // 82944
#define OG 16                 // output groups
#define OPG 2                 // outputs per thread

// ---------------------------------------------------------------------------
// K1: per-(i,pix) 9-bit PER-PIXEL live masks (no atomics: thread (pix,i) owns
// all 9 j bits, unconditional u16 store overwrites poisoned ws) + kv for live
// non-center taps + weight transpose to [tap][o][c] so pac's center weights
// are wave-uniform s_loads and sparse weights are contiguous per-lane gathers.
// Center tap (i=4,j=4) excluded: d=0 -> kv=1 exactly -> handled densely.
// ---------------------------------------------------------------------------
__global__ __launch_bounds__(256) void prep_k_kernel(
    const float* __restrict__ f,
    const float* __restrict__ W1, const float* __restrict__ W2,
    float* __restrict__ kbuf, unsigned short* __restrict__ mask9,
    float* __restrict__ W1t, float* __restrict__ W2t)
{
    const int i = blockIdx.y;
    if (i == KS) {                       // 64 blocks: transpose both weights
        for (int t = blockIdx.x * 256 + threadIdx.x; t < NW; t += 64 * 256) {
            int o = t / (NC * TAPS);
            int r = t - o * (NC * TAPS);
            int c = r / TAPS;
            int tap = r - c * TAPS;
            int d = (tap * NO + o) * NC + c;    // [tap][o][c]
            W1t[d] = W1[t];
            W2t[d] = W2[t];
        }
        return;
    }
    const int pix = blockIdx.x * 256 + threadIdx.x;
    const int h = pix >> 7, w = pix & (WW - 1);

    float fc[NC];
#pragma unroll
    for (int c = 0; c < NC; ++c) fc[c] = f[c * NPIX + pix];

    const int qh = h + i * DIL - PAD;
    const bool vh = (unsigned)qh < HH;
    unsigned pmask = 0;
#pragma unroll
    for (int j = 0; j < KS; ++j) {
        int qw = w + j * DIL - PAD;
        bool valid = vh & ((unsigned)qw < WW);
        int q = valid ? (qh * WW + qw) : pix;   // safe addr for masked lanes
        float s0 = 0.f, s1 = 0.f, s2 = 0.f, s3 = 0.f;
#pragma unroll
        for (int c4 = 0; c4 < 8; ++c4) {
            float d0 = f[(4 * c4 + 0) * NPIX + q] - fc[4 * c4 + 0];
            float d1 = f[(4 * c4 + 1) * NPIX + q] - fc[4 * c4 + 1];
            float d2 = f[(4 * c4 + 2) * NPIX + q] - fc[4 * c4 + 2];
            float d3 = f[(4 * c4 + 3) * NPIX + q] - fc[4 * c4 + 3];
            s0 = fmaf(d0, d0, s0); s1 = fmaf(d1, d1, s1);
            s2 = fmaf(d2, d2, s2); s3 = fmaf(d3, d3, s3);
        }
        float s = (s0 + s1) + (s2 + s3);
        // OOB taps contribute 0 in pacconv (x zero-padded) -> drop exactly.
        bool live = valid && (s <= SMAX) && !(i == 4 && j == 4);
        if (live) {
            pmask |= 1u << j;
            kbuf[(i * KS + j) * NPIX + pix] = __expf(-0.5f * s);
        }
    }
    mask9[i * NPIX + pix] = (unsigned short)pmask;   // unconditional: kills poison
}

// ---------------------------------------------------------------------------
// pac: dense exact center (kv=1) 1x1 conv + per-LANE sparse residual over the
// pixel's own live taps (~0.18/pixel avg). Wave loop length = max per-lane
// count (~1-3) instead of ~10 wave-uniform taps. OPG=2/OG=16 doubles TLP.
// ---------------------------------------------------------------------------
__global__ __launch_bounds__(256) void pac_kernel(
    const float* __restrict__ in, const float* __restrict__ kbuf,
    const unsigned short* __restrict__ mask9, const float* __restrict__ Wt,
    const float* __restrict__ bias, float* __restrict__ out)
{
    const int pix = blockIdx.x * 256 + threadIdx.x;
    const int ob = blockIdx.y * OPG;

    // Build the pixel's 81-bit live mask (center bit never set by prep).
    unsigned long long M0 = 0ull;
    unsigned M1;
#pragma unroll
    for (int i = 0; i < 7; ++i)
        M0 |= (unsigned long long)mask9[i * NPIX + pix] << (9 * i);
    {
        unsigned mk7 = mask9[7 * NPIX + pix];      // taps 63..71 straddle
        unsigned mk8 = mask9[8 * NPIX + pix];      // taps 72..80
        M0 |= (unsigned long long)(mk7 & 1u) << 63;
        M1 = (mk7 >> 1) | (mk8 << 8);
    }

    // Dense center: wave-uniform weights -> s_loads.
    const float* __restrict__ wc = Wt + (40 * NO + ob) * NC;
    float a0 = 0.f, a1 = 0.f;
    {
        float x0[NC];
#pragma unroll
        for (int c = 0; c < NC; ++c) x0[c] = in[c * NPIX + pix];
#pragma unroll
        for (int c = 0; c < NC; ++c) {
            a0 = fmaf(x0[c], wc[c], a0);
            a1 = fmaf(x0[c], wc[NC + c], a1);
        }
    }

#define SPARSE_TAP(T) do {                                                 \
        int ii_ = (T) / 9, jj_ = (T) - 9 * ii_;                            \
        int q_ = pix + (ii_ * DIL - PAD) * WW + (jj_ * DIL - PAD);         \
        float kv_ = kbuf[(T) * NPIX + pix];                                \
        const float* wp_ = Wt + ((T) * NO + ob) * NC;                      \
        float t0_ = 0.f, t1_ = 0.f;                                        \
        _Pragma("unroll")                                                  \
        for (int c = 0; c < NC; ++c) {                                     \
            float xv_ = in[c * NPIX + q_];                                 \
            t0_ = fmaf(xv_, wp_[c], t0_);                                  \
            t1_ = fmaf(xv_, wp_[NC + c], t1_);                             \
        }                                                                  \
        a0 = fmaf(kv_, t0_, a0);                                           \
        a1 = fmaf(kv_, t1_, a1);                                           \
    } while (0)

    while (M0) {                        // per-lane divergent, rare
        int t = __builtin_ctzll(M0);
        M0 &= M0 - 1;
        SPARSE_TAP(t);
    }
    while (M1) {
        int t = 64 + __builtin_ctz(M1);
        M1 &= M1 - 1;
        SPARSE_TAP(t);
    }
#undef SPARSE_TAP

    out[(ob + 0) * NPIX + pix] = a0 + bias[ob + 0];
    out[(ob + 1) * NPIX + pix] = a1 + bias[ob + 1];
}

// ---------------------------------------------------------------------------
// Fallback (round-1 proven path, 2 MB ws) in case ws is small.
// ---------------------------------------------------------------------------
#define CHUNK 27
#define NCHUNK 3
#define KMIN 1e-6f
__global__ __launch_bounds__(256) void pac_layer_fuse(
    const float* __restrict__ in, const float* __restrict__ f,
    const float* __restrict__ Wt, const float* __restrict__ bias,
    float* __restrict__ out)
{
    __shared__ float wl[NC * CHUNK * 8];
    const int og = blockIdx.y;
    const int pix = blockIdx.x * 256 + threadIdx.x;
    const int h = pix >> 7, w = pix & (WW - 1);
    float acc[8];
#pragma unroll
    for (int i = 0; i < 8; ++i) acc[i] = 0.f;
    float fc[NC];
#pragma unroll
    for (int c = 0; c < NC; ++c) fc[c] = f[c * NPIX + pix];
    for (int ch = 0; ch < NCHUNK; ++ch) {
        __syncthreads();
        for (int idx = threadIdx.x; idx < NC * CHUNK * 8; idx += 256) {
            int t = idx % CHUNK;
            int c = (idx / CHUNK) % NC;
            int o = idx / (CHUNK * NC);
            wl[(c * CHUNK + t) * 8 + o] =
                Wt[(og * 8 + o) * (NC * TAPS) + c * TAPS + ch * CHUNK + t];
        }
        __syncthreads();
        for (int t = 0; t < CHUNK; ++t) {
            int tap = ch * CHUNK + t;
            int qh = h + (tap / KS) * DIL - PAD;
            int qw = w + (tap % KS) * DIL - PAD;
            bool valid = ((unsigned)qh < HH) & ((unsigned)qw < WW);
            int q = qh * WW + qw;
            float s = 0.f;
#pragma unroll
            for (int c = 0; c < NC; ++c) {
                float fn = valid ? f[c * NPIX + q] : 0.f;
                float d = fn - fc[c];
                s = fmaf(d, d, s);
            }
            float kv = __expf(-0.5f * s);
            if (__all((kv < KMIN) | (!valid))) continue;
            const float* wpp = &wl[t * 8];
#pragma unroll 8
            for (int c = 0; c < NC; ++c) {
                float v = valid ? in[c * NPIX + q] : 0.f;
                v *= kv;
#pragma unroll
                for (int o = 0; o < 8; ++o)
                    acc[o] = fmaf(v, wpp[c * CHUNK * 8 + o], acc[o]);
            }
        }
    }
#pragma unroll
    for (int o = 0; o < 8; ++o)
        out[(og * 8 + o) * NPIX + pix] = acc[o] + bias[og * 8 + o];
}

// ---------------------------------------------------------------------------
extern "C" void kernel_launch(void* const* d_in, const int* in_sizes, int n_in,
                              void* d_out, int out_size, void* d_ws, size_t ws_size,
                              hipStream_t stream)
{
    (void)in_sizes; (void)n_in; (void)out_size;
    const float* x  = (const float*)d_in[0];
    const float* f  = (const float*)d_in[1];
    const float* W1 = (const float*)d_in[2];
    const float* b1 = (const float*)d_in[3];
    const float* W2 = (const float*)d_in[4];
    const float* b2 = (const float*)d_in[5];
    float* out = (float*)d_out;

    float* ws = (float*)d_ws;
    float* kbuf = ws;                                        // TAPS*NPIX floats
    unsigned short* mask9 = (unsigned short*)(ws + TAPS * NPIX); // KS*NPIX u16
    float* W1t = ws + TAPS * NPIX + (KS * NPIX) / 2;         // NW
    float* W2t = W1t + NW;                                   // NW
    float* ht  = W2t + NW;                                   // NO*NPIX
    const size_t need =
        (size_t)(TAPS * NPIX + (KS * NPIX) / 2 + 2 * NW + NO * NPIX) * sizeof(float);

    if (ws_size >= need) {
        prep_k_kernel<<<dim3(64, KS + 1), 256, 0, stream>>>(
            f, W1, W2, kbuf, mask9, W1t, W2t);
        pac_kernel<<<dim3(64, OG), 256, 0, stream>>>(x,  kbuf, mask9, W1t, b1, ht);
        pac_kernel<<<dim3(64, OG), 256, 0, stream>>>(ht, kbuf, mask9, W2t, b2, out);
    } else {
        float* hbuf = ws;
        pac_layer_fuse<<<dim3(64, 4), 256, 0, stream>>>(x, f, W1, b1, hbuf);
        pac_layer_fuse<<<dim3(64, 4), 256, 0, stream>>>(hbuf, f, W2, b2, out);
    }
}